// Round 2
// baseline (907.678 us; speedup 1.0000x reference)
//
#include <hip/hip_runtime.h>

constexpr float NEG_SLOPE = 0.2f;
constexpr float EPS = 1e-16f;

// ---------------- CSR build ----------------

__global__ void count_k(const int* __restrict__ dst, int* __restrict__ cnt, int E) {
    int i = blockIdx.x * blockDim.x + threadIdx.x;
    if (i < E) atomicAdd(&cnt[dst[i]], 1);
}

__global__ void scan1_k(const int* __restrict__ in, int* __restrict__ out,
                        int* __restrict__ bsum, int n) {
    __shared__ int s[256];
    int tid = threadIdx.x;
    int i = blockIdx.x * 256 + tid;
    int v = (i < n) ? in[i] : 0;
    s[tid] = v;
    __syncthreads();
    #pragma unroll
    for (int off = 1; off < 256; off <<= 1) {
        int t = (tid >= off) ? s[tid - off] : 0;
        __syncthreads();
        s[tid] += t;
        __syncthreads();
    }
    if (i < n) out[i] = s[tid] - v;
    if (tid == 255) bsum[blockIdx.x] = s[255];
}

__global__ void scan2_k(int* __restrict__ bsum, int nb) {
    __shared__ int s[1024];
    int tid = threadIdx.x;
    int v = (tid < nb) ? bsum[tid] : 0;
    s[tid] = v;
    __syncthreads();
    #pragma unroll
    for (int off = 1; off < 1024; off <<= 1) {
        int t = (tid >= off) ? s[tid - off] : 0;
        __syncthreads();
        s[tid] += t;
        __syncthreads();
    }
    if (tid < nb) bsum[tid] = s[tid] - v;
}

__global__ void scan3_k(int* __restrict__ rowptr, const int* __restrict__ bsum,
                        int n, int E) {
    int i = blockIdx.x * 256 + threadIdx.x;
    if (i < n) rowptr[i] += bsum[blockIdx.x];
    if (i == 0) rowptr[n] = E;
}

__global__ void fill_k(const int* __restrict__ src, const int* __restrict__ dst,
                       const int* __restrict__ rowptr, int* __restrict__ fill,
                       int* __restrict__ ssrc, int* __restrict__ seid, int E) {
    int i = blockIdx.x * blockDim.x + threadIdx.x;
    if (i < E) {
        int d = dst[i];
        int pos = rowptr[d] + atomicAdd(&fill[d], 1);
        ssrc[pos] = src[i];
        seid[pos] = i;
    }
}

// permute edge_attr into CSR slot order: eperm[k] = ea[seid[k]] (16 floats)
__global__ void permute_k(const float* __restrict__ ea, const int* __restrict__ seid,
                          float* __restrict__ eperm, int E) {
    int t = blockIdx.x * blockDim.x + threadIdx.x;   // t = k*4 + c
    if (t >= E * 4) return;
    int k = t >> 2, c = t & 3;
    const float4* srcr = reinterpret_cast<const float4*>(ea) + (size_t)seid[k] * 4;
    reinterpret_cast<float4*>(eperm)[(size_t)k * 4 + c] = srcr[c];
}

// mean incoming edge_attr per node (reads CSR-ordered eperm or gathers via seid)
template <int PERM>
__global__ void mean_k(const float* __restrict__ ea, const int* __restrict__ seid,
                       const int* __restrict__ rowptr, float* __restrict__ mattr, int N) {
    int t = blockIdx.x * blockDim.x + threadIdx.x;
    if (t >= N * 16) return;
    int v = t >> 4, f = t & 15;
    int s = rowptr[v], e = rowptr[v + 1];
    float sum = 0.f;
    for (int k = s; k < e; k++) {
        size_t row = PERM ? (size_t)k : (size_t)seid[k];
        sum += ea[row * 16 + f];
    }
    int c = e - s;
    mattr[t] = sum / (float)(c > 1 ? c : 1);
}

// ---------------- node transforms: xl = x@Wl+bl, xr = x@Wr+br ----------------

__global__ __launch_bounds__(256) void xfrm_k(
        const float* __restrict__ x,
        const float* __restrict__ Wl, const float* __restrict__ bl,
        const float* __restrict__ Wr, const float* __restrict__ br,
        float* __restrict__ xl, float* __restrict__ xr, int N) {
    __shared__ float sWl[64 * 64];
    __shared__ float sWr[64 * 64];
    for (int i = threadIdx.x; i < 64 * 64; i += 256) {
        sWl[i] = Wl[i];
        sWr[i] = Wr[i];
    }
    __syncthreads();
    int v = blockIdx.x * 4 + (threadIdx.x >> 6);
    int h = threadIdx.x & 63;
    if (v >= N) return;
    const float4* xrow = reinterpret_cast<const float4*>(x + (size_t)v * 64);
    float al = bl[h], ar = br[h];
    #pragma unroll
    for (int d4 = 0; d4 < 16; d4++) {
        float4 xv = xrow[d4];
        int d = d4 * 4;
        al = fmaf(xv.x, sWl[(d + 0) * 64 + h], al);
        al = fmaf(xv.y, sWl[(d + 1) * 64 + h], al);
        al = fmaf(xv.z, sWl[(d + 2) * 64 + h], al);
        al = fmaf(xv.w, sWl[(d + 3) * 64 + h], al);
        ar = fmaf(xv.x, sWr[(d + 0) * 64 + h], ar);
        ar = fmaf(xv.y, sWr[(d + 1) * 64 + h], ar);
        ar = fmaf(xv.z, sWr[(d + 2) * 64 + h], ar);
        ar = fmaf(xv.w, sWr[(d + 3) * 64 + h], ar);
    }
    xl[(size_t)v * 64 + h] = al;
    xr[(size_t)v * 64 + h] = ar;
}

// ---------------- per-node GATv2 aggregation (flash-style online softmax) ----------------

__device__ __forceinline__ float dot16(const float4* __restrict__ q,
                                       const float* __restrict__ wec) {
    float4 q0 = q[0], q1 = q[1], q2 = q[2], q3 = q[3];
    float ee = q0.x * wec[0];
    ee = fmaf(q0.y, wec[1], ee);
    ee = fmaf(q0.z, wec[2], ee);
    ee = fmaf(q0.w, wec[3], ee);
    ee = fmaf(q1.x, wec[4], ee);
    ee = fmaf(q1.y, wec[5], ee);
    ee = fmaf(q1.z, wec[6], ee);
    ee = fmaf(q1.w, wec[7], ee);
    ee = fmaf(q2.x, wec[8], ee);
    ee = fmaf(q2.y, wec[9], ee);
    ee = fmaf(q2.z, wec[10], ee);
    ee = fmaf(q2.w, wec[11], ee);
    ee = fmaf(q3.x, wec[12], ee);
    ee = fmaf(q3.y, wec[13], ee);
    ee = fmaf(q3.z, wec[14], ee);
    ee = fmaf(q3.w, wec[15], ee);
    return ee;
}

// MODE 0: write h1 = relu(out). MODE 1: fuse relu + JK-cat readout -> d_out[v].
// PERM 1: edge attrs are CSR-ordered (eperm); PERM 0: gather via seid.
template <int MODE, int PERM>
__global__ __launch_bounds__(256) void node_k(
        const float* __restrict__ xl, const float* __restrict__ xr,
        const float* __restrict__ ea, const int* __restrict__ seid,
        const float* __restrict__ mattr,
        const int* __restrict__ ssrc, const int* __restrict__ rowptr,
        const float* __restrict__ We, const float* __restrict__ att,
        const float* __restrict__ bc,
        float* __restrict__ hout,
        const float* __restrict__ h1, const float* __restrict__ Wout,
        const float* __restrict__ bout, float* __restrict__ out, int N) {
    int lane = threadIdx.x & 63;
    int v = blockIdx.x * 4 + (threadIdx.x >> 6);
    if (v >= N) return;

    float wec[16];
    #pragma unroll
    for (int d = 0; d < 16; d++) wec[d] = We[d * 64 + lane];
    float att_h = att[lane];
    float xr_h = xr[(size_t)v * 64 + lane];

    int s = rowptr[v], e = rowptr[v + 1];
    float m = -1e30f, denom = 0.f, acc = 0.f;

    int k = s;
    // ---- 4-edge unrolled main loop: independent gather + dot + butterfly chains
    for (; k + 4 <= e; k += 4) {
        int s0 = ssrc[k], s1 = ssrc[k + 1], s2 = ssrc[k + 2], s3 = ssrc[k + 3];
        const float4* r0;
        const float4* r1;
        const float4* r2;
        const float4* r3;
        if (PERM) {
            const float4* base = reinterpret_cast<const float4*>(ea) + (size_t)k * 4;
            r0 = base; r1 = base + 4; r2 = base + 8; r3 = base + 12;
        } else {
            r0 = reinterpret_cast<const float4*>(ea) + (size_t)seid[k] * 4;
            r1 = reinterpret_cast<const float4*>(ea) + (size_t)seid[k + 1] * 4;
            r2 = reinterpret_cast<const float4*>(ea) + (size_t)seid[k + 2] * 4;
            r3 = reinterpret_cast<const float4*>(ea) + (size_t)seid[k + 3] * 4;
        }
        float xls0 = xl[(size_t)s0 * 64 + lane];
        float xls1 = xl[(size_t)s1 * 64 + lane];
        float xls2 = xl[(size_t)s2 * 64 + lane];
        float xls3 = xl[(size_t)s3 * 64 + lane];
        float ee0 = dot16(r0, wec);
        float ee1 = dot16(r1, wec);
        float ee2 = dot16(r2, wec);
        float ee3 = dot16(r3, wec);
        float m0 = xls0 + xr_h + ee0; m0 = (m0 > 0.f) ? m0 : NEG_SLOPE * m0;
        float m1 = xls1 + xr_h + ee1; m1 = (m1 > 0.f) ? m1 : NEG_SLOPE * m1;
        float m2 = xls2 + xr_h + ee2; m2 = (m2 > 0.f) ? m2 : NEG_SLOPE * m2;
        float m3 = xls3 + xr_h + ee3; m3 = (m3 > 0.f) ? m3 : NEG_SLOPE * m3;
        float p0 = att_h * m0, p1 = att_h * m1, p2 = att_h * m2, p3 = att_h * m3;
        #pragma unroll
        for (int off = 32; off; off >>= 1) {
            p0 += __shfl_xor(p0, off);
            p1 += __shfl_xor(p1, off);
            p2 += __shfl_xor(p2, off);
            p3 += __shfl_xor(p3, off);
        }
        float mx = fmaxf(fmaxf(fmaxf(p0, p1), fmaxf(p2, p3)), m);
        float sc = __expf(m - mx);
        float w0 = __expf(p0 - mx);
        float w1 = __expf(p1 - mx);
        float w2 = __expf(p2 - mx);
        float w3 = __expf(p3 - mx);
        denom = denom * sc + ((w0 + w1) + (w2 + w3));
        acc = acc * sc + (fmaf(w0, xls0, w1 * xls1) + fmaf(w2, xls2, w3 * xls3));
        m = mx;
    }
    // ---- tail edges + self-loop (k == e)
    for (; k <= e; k++) {
        int srcn;
        const float4* q;
        if (k < e) {
            srcn = ssrc[k];
            size_t row = PERM ? (size_t)k : (size_t)seid[k];
            q = reinterpret_cast<const float4*>(ea) + row * 4;
        } else {
            srcn = v;
            q = reinterpret_cast<const float4*>(mattr) + (size_t)v * 4;
        }
        float ee = dot16(q, wec);
        float xls = xl[(size_t)srcn * 64 + lane];
        float mv = xls + xr_h + ee;
        mv = (mv > 0.f) ? mv : NEG_SLOPE * mv;
        float p = att_h * mv;
        #pragma unroll
        for (int off = 32; off; off >>= 1) p += __shfl_xor(p, off);
        float mnew = fmaxf(m, p);
        float sc = __expf(m - mnew);
        float w = __expf(p - mnew);
        denom = denom * sc + w;
        acc = acc * sc + w * xls;
        m = mnew;
    }

    float res = acc / (denom + EPS) + bc[lane];
    res = fmaxf(res, 0.f);

    if (MODE == 0) {
        hout[(size_t)v * 64 + lane] = res;
    } else {
        float part = h1[(size_t)v * 64 + lane] * Wout[lane] + res * Wout[64 + lane];
        #pragma unroll
        for (int off = 32; off; off >>= 1) part += __shfl_xor(part, off);
        if (lane == 0) out[v] = part + bout[0];
    }
}

// ---------------- launch ----------------

extern "C" void kernel_launch(void* const* d_in, const int* in_sizes, int n_in,
                              void* d_out, int out_size, void* d_ws, size_t ws_size,
                              hipStream_t stream) {
    const float* x     = (const float*)d_in[0];
    const int*   eidx  = (const int*)d_in[1];
    const float* eattr = (const float*)d_in[2];
    const float* Wl1 = (const float*)d_in[4];
    const float* bl1 = (const float*)d_in[5];
    const float* Wr1 = (const float*)d_in[6];
    const float* br1 = (const float*)d_in[7];
    const float* We1 = (const float*)d_in[8];
    const float* att1 = (const float*)d_in[9];
    const float* bc1 = (const float*)d_in[10];
    const float* Wl2 = (const float*)d_in[11];
    const float* bl2 = (const float*)d_in[12];
    const float* Wr2 = (const float*)d_in[13];
    const float* br2 = (const float*)d_in[14];
    const float* We2 = (const float*)d_in[15];
    const float* att2 = (const float*)d_in[16];
    const float* bc2 = (const float*)d_in[17];
    const float* Wout = (const float*)d_in[18];
    const float* bout = (const float*)d_in[19];

    int N = in_sizes[0] / 64;
    int E = in_sizes[1] / 2;
    const int* srcA = eidx;
    const int* dstA = eidx + E;

    char* w = (char*)d_ws;
    size_t used = 0;
    auto alloc = [&](size_t bytes) {
        char* p = w + used;
        used += (bytes + 255) & ~size_t(255);
        return p;
    };
    int*   cnt    = (int*)alloc((size_t)N * 4);
    int*   fill   = (int*)alloc((size_t)N * 4);
    int*   rowptr = (int*)alloc((size_t)(N + 1) * 4);
    int*   bsum   = (int*)alloc(1024 * 4);
    int*   ssrc   = (int*)alloc((size_t)E * 4);
    int*   seid   = (int*)alloc((size_t)E * 4);
    float* mattr  = (float*)alloc((size_t)N * 16 * 4);
    float* xl     = (float*)alloc((size_t)N * 64 * 4);
    float* xr     = (float*)alloc((size_t)N * 64 * 4);
    float* h1     = (float*)alloc((size_t)N * 64 * 4);
    size_t eperm_bytes = (size_t)E * 16 * 4;
    bool perm = (used + eperm_bytes) <= ws_size;
    float* eperm = perm ? (float*)alloc(eperm_bytes) : nullptr;

    hipMemsetAsync(cnt, 0, (size_t)N * 4, stream);
    hipMemsetAsync(fill, 0, (size_t)N * 4, stream);

    int NB = (N + 255) / 256;
    count_k<<<(E + 255) / 256, 256, 0, stream>>>(dstA, cnt, E);
    scan1_k<<<NB, 256, 0, stream>>>(cnt, rowptr, bsum, N);
    scan2_k<<<1, 1024, 0, stream>>>(bsum, NB);
    scan3_k<<<NB, 256, 0, stream>>>(rowptr, bsum, N, E);
    fill_k<<<(E + 255) / 256, 256, 0, stream>>>(srcA, dstA, rowptr, fill, ssrc, seid, E);

    const float* eaN = eattr;
    if (perm) {
        permute_k<<<(E * 4 + 255) / 256, 256, 0, stream>>>(eattr, seid, eperm, E);
        eaN = eperm;
    }

    int nodeBlocks = (N + 3) / 4;
    if (perm) {
        mean_k<1><<<(N * 16 + 255) / 256, 256, 0, stream>>>(eaN, seid, rowptr, mattr, N);
        xfrm_k<<<nodeBlocks, 256, 0, stream>>>(x, Wl1, bl1, Wr1, br1, xl, xr, N);
        node_k<0, 1><<<nodeBlocks, 256, 0, stream>>>(xl, xr, eaN, seid, mattr, ssrc, rowptr,
                                                     We1, att1, bc1, h1,
                                                     nullptr, nullptr, nullptr, nullptr, N);
        xfrm_k<<<nodeBlocks, 256, 0, stream>>>(h1, Wl2, bl2, Wr2, br2, xl, xr, N);
        node_k<1, 1><<<nodeBlocks, 256, 0, stream>>>(xl, xr, eaN, seid, mattr, ssrc, rowptr,
                                                     We2, att2, bc2, nullptr,
                                                     h1, Wout, bout, (float*)d_out, N);
    } else {
        mean_k<0><<<(N * 16 + 255) / 256, 256, 0, stream>>>(eaN, seid, rowptr, mattr, N);
        xfrm_k<<<nodeBlocks, 256, 0, stream>>>(x, Wl1, bl1, Wr1, br1, xl, xr, N);
        node_k<0, 0><<<nodeBlocks, 256, 0, stream>>>(xl, xr, eaN, seid, mattr, ssrc, rowptr,
                                                     We1, att1, bc1, h1,
                                                     nullptr, nullptr, nullptr, nullptr, N);
        xfrm_k<<<nodeBlocks, 256, 0, stream>>>(h1, Wl2, bl2, Wr2, br2, xl, xr, N);
        node_k<1, 0><<<nodeBlocks, 256, 0, stream>>>(xl, xr, eaN, seid, mattr, ssrc, rowptr,
                                                     We2, att2, bc2, nullptr,
                                                     h1, Wout, bout, (float*)d_out, N);
    }
}